// Round 1
// baseline (102.808 us; speedup 1.0000x reference)
//
#include <hip/hip_runtime.h>

#define BB 8
#define CC 20
#define HH 384
#define WW 384
#define NPIX (BB*HH*WW)
#define BIGF 1.0e6f
#define PADSQ 3.0e12f
#define WIN 32

// Kernel 1: vertical EDT pass for both masks (t==0 and t==1).
// One thread per (b, x) column; classic forward/backward 1D distance scan.
// Leaves d1^2 (squared vertical distance, clamped at BIG) in w0/w1.
__global__ __launch_bounds__(256) void edt_vertical(const int* __restrict__ tgt,
                                                    float* __restrict__ w0,
                                                    float* __restrict__ w1) {
    int tid = blockIdx.x * blockDim.x + threadIdx.x;
    if (tid >= BB * WW) return;
    int b = tid / WW, x = tid % WW;
    const int* tp = tgt + b * HH * WW + x;
    float* p0 = w0 + b * HH * WW + x;
    float* p1 = w1 + b * HH * WW + x;

    float a0 = BIGF, a1 = BIGF;
    #pragma unroll 4
    for (int y = 0; y < HH; ++y) {
        int t = tp[y * WW];
        float c0 = (t == 0) ? 0.0f : BIGF;
        float c1 = (t == 1) ? 0.0f : BIGF;
        a0 = fminf(c0, a0 + 1.0f);
        a1 = fminf(c1, a1 + 1.0f);
        p0[y * WW] = a0;
        p1[y * WW] = a1;
    }
    float b0 = BIGF, b1 = BIGF;
    #pragma unroll 4
    for (int y = HH - 1; y >= 0; --y) {
        float f0 = p0[y * WW];
        float f1 = p1[y * WW];
        b0 = fminf(f0, b0 + 1.0f);
        b1 = fminf(f1, b1 + 1.0f);
        float d0 = fminf(b0, BIGF);
        float d1 = fminf(b1, BIGF);
        p0[y * WW] = d0 * d0;
        p1[y * WW] = d1 * d1;
    }
}

// Kernel 2: per-row horizontal min-plus (windowed +-32, exact when dist<=32;
// beyond that exp(-dist/3) underflows identically to the reference), weight,
// fused CE over 20 channels, block reduction -> bsum[row].
__global__ __launch_bounds__(WW) void loss_rows(const float* __restrict__ pred,
                                                const int* __restrict__ tgt,
                                                const float* __restrict__ w0,
                                                const float* __restrict__ w1,
                                                float* __restrict__ bsum) {
    __shared__ float s0[WW + 2 * WIN];
    __shared__ float s1[WW + 2 * WIN];
    __shared__ float wred[WW / 64];

    int row = blockIdx.x;            // b*HH + y
    int x = threadIdx.x;             // 0..383
    int base = row * WW;

    s0[WIN + x] = w0[base + x];
    s1[WIN + x] = w1[base + x];
    if (x < WIN) { s0[x] = PADSQ; s1[x] = PADSQ; }
    if (x >= WW - WIN) { s0[x + 2 * WIN] = PADSQ; s1[x + 2 * WIN] = PADSQ; }
    __syncthreads();

    // windowed min-plus with parabola
    float m0 = PADSQ, m1 = PADSQ;
    float dx = (float)WIN;
    #pragma unroll
    for (int j = 0; j <= 2 * WIN; ++j) {
        float dsq = dx * dx;
        m0 = fminf(m0, dsq + s0[x + j]);
        m1 = fminf(m1, dsq + s1[x + j]);
        dx -= 1.0f;
    }
    float dist = sqrtf(m0) + sqrtf(m1);
    float wgt = 1.0f + 5.0f * __expf(dist * (-1.0f / 3.0f));

    // fused cross-entropy
    int b = row / HH;
    int t = tgt[base + x];
    const float* pbase = pred + (b * CC * HH * WW) + (row % HH) * WW + x;
    float pv[CC];
    float mx = -1.0e30f;
    #pragma unroll
    for (int c = 0; c < CC; ++c) {
        pv[c] = pbase[c * HH * WW];
        mx = fmaxf(mx, pv[c]);
    }
    float S = 0.0f;
    float pt = 0.0f;
    #pragma unroll
    for (int c = 0; c < CC; ++c) {
        S += __expf(pv[c] - mx);
        pt = (c == t) ? pv[c] : pt;
    }
    float ce = mx + __logf(S) - pt;
    float val = ce * wgt;

    // deterministic block reduction (wave shfl + LDS)
    #pragma unroll
    for (int off = 32; off; off >>= 1) val += __shfl_down(val, off);
    int wid = threadIdx.x >> 6;
    int lane = threadIdx.x & 63;
    if (lane == 0) wred[wid] = val;
    __syncthreads();
    if (threadIdx.x == 0) {
        float s = 0.0f;
        #pragma unroll
        for (int i = 0; i < WW / 64; ++i) s += wred[i];
        bsum[row] = s;
    }
}

// Kernel 3: deterministic final reduction of 3072 block sums -> mean.
__global__ __launch_bounds__(1024) void finalize(const float* __restrict__ bsum,
                                                 float* __restrict__ out) {
    __shared__ float red[16];
    int tid = threadIdx.x;
    float v = 0.0f;
    #pragma unroll
    for (int i = 0; i < 3; ++i) v += bsum[tid + i * 1024];
    #pragma unroll
    for (int off = 32; off; off >>= 1) v += __shfl_down(v, off);
    int wid = tid >> 6, lane = tid & 63;
    if (lane == 0) red[wid] = v;
    __syncthreads();
    if (tid == 0) {
        float s = 0.0f;
        #pragma unroll
        for (int i = 0; i < 16; ++i) s += red[i];
        out[0] = s * (1.0f / (float)NPIX);
    }
}

extern "C" void kernel_launch(void* const* d_in, const int* in_sizes, int n_in,
                              void* d_out, int out_size, void* d_ws, size_t ws_size,
                              hipStream_t stream) {
    const float* pred = (const float*)d_in[0];
    const int* tgt = (const int*)d_in[1];
    float* out = (float*)d_out;

    float* w0 = (float*)d_ws;
    float* w1 = w0 + (size_t)NPIX;
    float* bsum = w1 + (size_t)NPIX;   // BB*HH = 3072 floats

    edt_vertical<<<(BB * WW + 255) / 256, 256, 0, stream>>>(tgt, w0, w1);
    loss_rows<<<BB * HH, WW, 0, stream>>>(pred, tgt, w0, w1, bsum);
    finalize<<<1, 1024, 0, stream>>>(bsum, out);
}

// Round 2
// 46.091 us; speedup vs baseline: 2.2305x; 2.2305x over previous
//
#include <hip/hip_runtime.h>

#define BB 8
#define CC 20
#define HH 384
#define WW 384
#define NPIX (BB*HH*WW)
#define BIGF 1.0e6f
#define PADSQ 3.0e12f
#define INFF 1.0e30f
#define WIN 32

// Kernel 1: vertical EDT for both masks, wave-parallel prefix/suffix min-scan.
// One wave per (b,x) column: lane l owns rows y = 6l..6l+5.
//   fwd[y] = y + min_{y'<=y}(c[y'] - y'),  bwd[y] = -y + min_{y'>=y}(c[y'] + y')
//   d1[y] = min(fwd,bwd)  (== reference's min(d1, BIG) exactly; see notes)
// Writes d1^2 to w0/w1. Grid: 3072 waves = 768 blocks x 4 waves.
__global__ __launch_bounds__(256) void edt_vertical(const int* __restrict__ tgt,
                                                    float* __restrict__ w0,
                                                    float* __restrict__ w1) {
    int lane = threadIdx.x & 63;
    int col = blockIdx.x * 4 + (threadIdx.x >> 6);   // 0..3071, exact
    int b = col / WW, x = col % WW;
    const int* tp = tgt + (size_t)b * HH * WW + x;
    int y0 = lane * 6;

    int tv[6];
    #pragma unroll
    for (int k = 0; k < 6; ++k) tv[k] = tp[(y0 + k) * WW];

    float* outp0 = w0 + (size_t)b * HH * WW + x;
    float* outp1 = w1 + (size_t)b * HH * WW + x;

    #pragma unroll
    for (int m = 0; m < 2; ++m) {
        // forward values v = c - y', local inclusive prefix min
        float p[6];
        float run = INFF;
        #pragma unroll
        for (int k = 0; k < 6; ++k) {
            float c = (tv[k] == m) ? 0.0f : BIGF;
            run = fminf(run, c - (float)(y0 + k));
            p[k] = run;
        }
        // wave inclusive min-scan over lane totals
        float s = run;
        #pragma unroll
        for (int off = 1; off < 64; off <<= 1) {
            float o = __shfl_up(s, off);
            if (lane >= off) s = fminf(s, o);
        }
        float carry = __shfl_up(s, 1);
        if (lane == 0) carry = INFF;

        // backward values u = c + y', local inclusive suffix min
        float q[6];
        run = INFF;
        #pragma unroll
        for (int k = 5; k >= 0; --k) {
            float c = (tv[k] == m) ? 0.0f : BIGF;
            run = fminf(run, c + (float)(y0 + k));
            q[k] = run;
        }
        float sb = run;
        #pragma unroll
        for (int off = 1; off < 64; off <<= 1) {
            float o = __shfl_down(sb, off);
            if (lane < 64 - off) sb = fminf(sb, o);
        }
        float carryb = __shfl_down(sb, 1);
        if (lane == 63) carryb = INFF;

        float* op = (m == 0) ? outp0 : outp1;
        #pragma unroll
        for (int k = 0; k < 6; ++k) {
            float y = (float)(y0 + k);
            float fwd = y + fminf(carry, p[k]);
            float bwd = fminf(carryb, q[k]) - y;
            float d = fminf(fwd, bwd);     // == min(dist-to-zero, BIG) exactly
            op[(y0 + k) * WW] = d * d;
        }
    }
}

// Kernel 2: per-row horizontal min-plus (windowed +-32, exact when dist<=32;
// beyond that exp underflow makes w==1.0 identically), weight, fused CE over
// 20 channels, deterministic block reduction -> bsum[row].
__global__ __launch_bounds__(WW) void loss_rows(const float* __restrict__ pred,
                                                const int* __restrict__ tgt,
                                                const float* __restrict__ w0,
                                                const float* __restrict__ w1,
                                                float* __restrict__ bsum) {
    __shared__ float s0[WW + 2 * WIN];
    __shared__ float s1[WW + 2 * WIN];
    __shared__ float wred[WW / 64];

    int row = blockIdx.x;            // b*HH + y
    int x = threadIdx.x;             // 0..383
    int base = row * WW;

    s0[WIN + x] = w0[base + x];
    s1[WIN + x] = w1[base + x];
    if (x < WIN) { s0[x] = PADSQ; s1[x] = PADSQ; }
    if (x >= WW - WIN) { s0[x + 2 * WIN] = PADSQ; s1[x + 2 * WIN] = PADSQ; }
    __syncthreads();

    float m0 = PADSQ, m1 = PADSQ;
    float dx = (float)WIN;
    #pragma unroll
    for (int j = 0; j <= 2 * WIN; ++j) {
        float dsq = dx * dx;
        m0 = fminf(m0, dsq + s0[x + j]);
        m1 = fminf(m1, dsq + s1[x + j]);
        dx -= 1.0f;
    }
    float dist = sqrtf(m0) + sqrtf(m1);
    float wgt = 1.0f + 5.0f * __expf(dist * (-1.0f / 3.0f));

    int b = row / HH;
    int t = tgt[base + x];
    const float* pbase = pred + (size_t)b * CC * HH * WW + (row % HH) * WW + x;
    float pv[CC];
    float mx = -1.0e30f;
    #pragma unroll
    for (int c = 0; c < CC; ++c) {
        pv[c] = pbase[(size_t)c * HH * WW];
        mx = fmaxf(mx, pv[c]);
    }
    float S = 0.0f;
    float pt = 0.0f;
    #pragma unroll
    for (int c = 0; c < CC; ++c) {
        S += __expf(pv[c] - mx);
        pt = (c == t) ? pv[c] : pt;
    }
    float ce = mx + __logf(S) - pt;
    float val = ce * wgt;

    #pragma unroll
    for (int off = 32; off; off >>= 1) val += __shfl_down(val, off);
    int wid = threadIdx.x >> 6;
    int lane = threadIdx.x & 63;
    if (lane == 0) wred[wid] = val;
    __syncthreads();
    if (threadIdx.x == 0) {
        float s = 0.0f;
        #pragma unroll
        for (int i = 0; i < WW / 64; ++i) s += wred[i];
        bsum[row] = s;
    }
}

// Kernel 3: deterministic final reduction of 3072 block sums -> mean.
__global__ __launch_bounds__(1024) void finalize(const float* __restrict__ bsum,
                                                 float* __restrict__ out) {
    __shared__ float red[16];
    int tid = threadIdx.x;
    float v = 0.0f;
    #pragma unroll
    for (int i = 0; i < 3; ++i) v += bsum[tid + i * 1024];
    #pragma unroll
    for (int off = 32; off; off >>= 1) v += __shfl_down(v, off);
    int wid = tid >> 6, lane = tid & 63;
    if (lane == 0) red[wid] = v;
    __syncthreads();
    if (tid == 0) {
        float s = 0.0f;
        #pragma unroll
        for (int i = 0; i < 16; ++i) s += red[i];
        out[0] = s * (1.0f / (float)NPIX);
    }
}

extern "C" void kernel_launch(void* const* d_in, const int* in_sizes, int n_in,
                              void* d_out, int out_size, void* d_ws, size_t ws_size,
                              hipStream_t stream) {
    const float* pred = (const float*)d_in[0];
    const int* tgt = (const int*)d_in[1];
    float* out = (float*)d_out;

    float* w0 = (float*)d_ws;
    float* w1 = w0 + (size_t)NPIX;
    float* bsum = w1 + (size_t)NPIX;   // BB*HH = 3072 floats

    edt_vertical<<<(BB * WW) / 4, 256, 0, stream>>>(tgt, w0, w1);
    loss_rows<<<BB * HH, WW, 0, stream>>>(pred, tgt, w0, w1, bsum);
    finalize<<<1, 1024, 0, stream>>>(bsum, out);
}